// Round 5
// baseline (716.658 us; speedup 1.0000x reference)
//
#include <hip/hip_runtime.h>
#include <math.h>

#define N 4096
#define NHEAD 4
#define SPLIT_ATT 8
#define SPLIT_G 8

// ------------------------------------------------------------------
// bitmask pre-pass: bmw[i][w] bit j = (adj[i][w*32+j] != 0)
__global__ __launch_bounds__(256) void k_bm(const int* __restrict__ adj,
    unsigned int* __restrict__ bmw) {
  const int lane = threadIdx.x & 63;
  const int wid = threadIdx.x >> 6;
  const long total = (long)N * N / 64;       // 64-element groups
  long g = (long)blockIdx.x * 4 + wid;
  const long stride = (long)gridDim.x * 4;
  for (; g < total; g += stride) {
    int e = adj[g * 64 + lane];
    unsigned long long mask = __ballot(e != 0);
    if (lane == 0)  bmw[g * 2]     = (unsigned int)(mask & 0xFFFFFFFFull);
    if (lane == 32) bmw[g * 2 + 1] = (unsigned int)(mask >> 32);
  }
}

// ------------------------------------------------------------------
// enc1: H1 = relu(LN(X[N,256] @ W[256,512] + b))
__global__ __launch_bounds__(512) void k_enc1(const float* __restrict__ X,
    const float* __restrict__ W, const float* __restrict__ b,
    const float* __restrict__ g, const float* __restrict__ be,
    float* __restrict__ out) {
  __shared__ float xs[8][256];
  __shared__ float hs[8][512];
  const int t = threadIdx.x;
  const int row0 = blockIdx.x * 8;
  {
    const float4* src = reinterpret_cast<const float4*>(X + row0 * 256);
    float4* dst = reinterpret_cast<float4*>(&xs[0][0]);
    dst[t] = src[t];
  }
  __syncthreads();
  float acc[8] = {0.f,0.f,0.f,0.f,0.f,0.f,0.f,0.f};
  for (int k = 0; k < 256; ++k) {
    float w = W[k * 512 + t];
#pragma unroll
    for (int r = 0; r < 8; ++r) acc[r] = fmaf(xs[r][k], w, acc[r]);
  }
  const float bb = b[t];
#pragma unroll
  for (int r = 0; r < 8; ++r) hs[r][t] = acc[r] + bb;
  __syncthreads();
  const int wv = t >> 6, lane = t & 63;
  float v0[8];
  float s1 = 0.f, s2 = 0.f;
#pragma unroll
  for (int kk = 0; kk < 8; ++kk) {
    float x = hs[wv][lane + 64 * kk];
    v0[kk] = x; s1 += x; s2 += x * x;
  }
#pragma unroll
  for (int off = 1; off < 64; off <<= 1) { s1 += __shfl_xor(s1, off); s2 += __shfl_xor(s2, off); }
  const float mean = s1 * (1.f / 512.f);
  const float var = s2 * (1.f / 512.f) - mean * mean;
  const float rstd = rsqrtf(var + 1e-5f);
#pragma unroll
  for (int kk = 0; kk < 8; ++kk) {
    int c = lane + 64 * kk;
    float y = g[c] * (v0[kk] - mean) * rstd + be[c];
    out[(row0 + wv) * 512 + c] = fmaxf(y, 0.f);
  }
}

// ------------------------------------------------------------------
// enc2: EMB = LN(H1[N,512] @ W[512,128] + b)
__global__ __launch_bounds__(128) void k_enc2(const float* __restrict__ X,
    const float* __restrict__ W, const float* __restrict__ b,
    const float* __restrict__ g, const float* __restrict__ be,
    float* __restrict__ out) {
  __shared__ float xs[8][512];
  __shared__ float hs[8][128];
  const int t = threadIdx.x;
  const int row0 = blockIdx.x * 8;
  {
    const float4* src = reinterpret_cast<const float4*>(X + row0 * 512);
    float4* dst = reinterpret_cast<float4*>(&xs[0][0]);
    for (int idx = t; idx < 1024; idx += 128) dst[idx] = src[idx];
  }
  __syncthreads();
  float acc[8] = {0.f,0.f,0.f,0.f,0.f,0.f,0.f,0.f};
  for (int k = 0; k < 512; ++k) {
    float w = W[k * 128 + t];
#pragma unroll
    for (int r = 0; r < 8; ++r) acc[r] = fmaf(xs[r][k], w, acc[r]);
  }
  const float bb = b[t];
#pragma unroll
  for (int r = 0; r < 8; ++r) hs[r][t] = acc[r] + bb;
  __syncthreads();
  const int wv = t >> 6, lane = t & 63;
  for (int rr = 0; rr < 4; ++rr) {
    int row = wv * 4 + rr;
    float a0 = hs[row][lane], a1 = hs[row][lane + 64];
    float s1 = a0 + a1, s2 = a0 * a0 + a1 * a1;
#pragma unroll
    for (int off = 1; off < 64; off <<= 1) { s1 += __shfl_xor(s1, off); s2 += __shfl_xor(s2, off); }
    float mean = s1 * (1.f / 128.f);
    float rstd = rsqrtf(s2 * (1.f / 128.f) - mean * mean + 1e-5f);
    out[(row0 + row) * 128 + lane]      = g[lane] * (a0 - mean) * rstd + be[lane];
    out[(row0 + row) * 128 + lane + 64] = g[lane + 64] * (a1 - mean) * rstd + be[lane + 64];
  }
}

// ------------------------------------------------------------------
// qkv v2: 512 thr, 16 rows/block, grp(4) x 4 rows, col = t&127
__global__ __launch_bounds__(512) void k_qkv(const float* __restrict__ emb,
    const float* __restrict__ Wq, const float* __restrict__ Wk, const float* __restrict__ Wv,
    float* __restrict__ q, float* __restrict__ k, float* __restrict__ v) {
  __shared__ float xs[16][128];
  const int t = threadIdx.x;
  const int col = t & 127;
  const int grp = t >> 7;          // 0..3 -> rows grp*4..grp*4+3
  const int row0 = blockIdx.x * 16;
  {
    const float4* src = reinterpret_cast<const float4*>(emb + row0 * 128);
    float4* dst = reinterpret_cast<float4*>(&xs[0][0]);
    dst[t] = src[t];               // 16*128/4 = 512
  }
  __syncthreads();
  float aq[4] = {0.f,0.f,0.f,0.f};
  float ak[4] = {0.f,0.f,0.f,0.f};
  float av[4] = {0.f,0.f,0.f,0.f};
  for (int kk = 0; kk < 128; ++kk) {
    float wq = Wq[kk * 128 + col], wk = Wk[kk * 128 + col], wv = Wv[kk * 128 + col];
#pragma unroll
    for (int r = 0; r < 4; ++r) {
      float x = xs[grp * 4 + r][kk];
      aq[r] = fmaf(x, wq, aq[r]);
      ak[r] = fmaf(x, wk, ak[r]);
      av[r] = fmaf(x, wv, av[r]);
    }
  }
#pragma unroll
  for (int r = 0; r < 4; ++r) {
    const int row = row0 + grp * 4 + r;
    q[row * 128 + col] = aq[r];
    k[row * 128 + col] = ak[r];
    v[row * 128 + col] = av[r];
  }
}

// ------------------------------------------------------------------
// ti[i] = sum_e tanh(temps[i,:] @ tW[:,e] + tb[e]) * wa[e]
__global__ __launch_bounds__(256) void k_ti(const float* __restrict__ temps,
    const float* __restrict__ tW, const float* __restrict__ tb,
    const float* __restrict__ wa, float* __restrict__ ti_out) {
  __shared__ float tws[1280];
  __shared__ float tbs[128], was[128];
  const int t = threadIdx.x;
  for (int idx = t; idx < 1280; idx += 256) tws[idx] = tW[idx];
  if (t < 128) { tbs[t] = tb[t]; was[t] = wa[t]; }
  __syncthreads();
  const int qi = t & 3;
  const int li = t >> 2;
  const int i = blockIdx.x * 64 + li;
  float tp[10];
#pragma unroll
  for (int c = 0; c < 10; ++c) tp[c] = temps[i * 10 + c];
  float acc = 0.f;
  const int e0 = qi * 32;
  for (int e = e0; e < e0 + 32; ++e) {
    float s = tbs[e];
#pragma unroll
    for (int c = 0; c < 10; ++c) s = fmaf(tp[c], tws[c * 128 + e], s);
    float th = 1.f - 2.f * __fdividef(1.f, __expf(2.f * s) + 1.f);
    acc = fmaf(th, was[e], acc);
  }
  acc += __shfl_xor(acc, 1);
  acc += __shfl_xor(acc, 2);
  if (qi == 0) ti_out[i] = acc;
}

// ------------------------------------------------------------------
// flash attention partial v4: branchless 2-pass sub-tile softmax + bitmask.
// Block 256 thr: wave = head (4), lane = i-row (64-row tile). j-tile 64,
// sub-tile 8. K/V LDS reads are wave-uniform broadcasts (conflict-free).
__global__ __launch_bounds__(256, 2) void k_attn(const float* __restrict__ q,
    const float* __restrict__ kk, const float* __restrict__ vv,
    const unsigned int* __restrict__ bmw,
    float* __restrict__ pacc, float* __restrict__ pml) {
  __shared__ float Kt[64][128];
  __shared__ float Vt[64][128];
  const int t = threadIdx.x;
  const int itile = blockIdx.x / SPLIT_ATT;
  const int split = blockIdx.x % SPLIT_ATT;
  const int h = t >> 6;
  const int row = t & 63;
  const int i = itile * 64 + row;
  const int dbase = h * 32;
  float4 q4[8];
  {
    const float4* qp = reinterpret_cast<const float4*>(q + (size_t)i * 128 + dbase);
#pragma unroll
    for (int u = 0; u < 8; ++u) q4[u] = qp[u];
  }
  float m = -1e30f, l = 0.f;
  float4 a[8];
#pragma unroll
  for (int u = 0; u < 8; ++u) a[u] = make_float4(0.f, 0.f, 0.f, 0.f);
  const int j0beg = split * (N / SPLIT_ATT);
  const int j0end = j0beg + (N / SPLIT_ATT);
  for (int j0 = j0beg; j0 < j0end; j0 += 64) {
    __syncthreads();   // protect LDS from previous tile's readers
    {
      const float4* ks = reinterpret_cast<const float4*>(kk + (size_t)j0 * 128);
      const float4* vs = reinterpret_cast<const float4*>(vv + (size_t)j0 * 128);
      float4* kd = reinterpret_cast<float4*>(&Kt[0][0]);
      float4* vd = reinterpret_cast<float4*>(&Vt[0][0]);
#pragma unroll
      for (int u = 0; u < 8; ++u) { kd[t + 256 * u] = ks[t + 256 * u]; vd[t + 256 * u] = vs[t + 256 * u]; }
    }
    // adjacency|eye bits for this lane's row, 64 j = 2 words
    const uint2 mw = *reinterpret_cast<const uint2*>(bmw + (size_t)i * 128 + (j0 >> 5));
    // eye bit: j == i in this tile?
    const int eyeoff = i - j0;   // in [0,64) if diagonal falls in tile
    __syncthreads();
    for (int sub = 0; sub < 8; ++sub) {
      const int jb = sub * 8;
      unsigned mbits = ((sub < 4 ? mw.x : mw.y) >> ((sub & 3) * 8)) & 0xFFu;
      if (((unsigned)(eyeoff - jb)) < 8u) mbits |= (1u << (eyeoff - jb));
      float sarr[8];
      // pass 1: scores
#pragma unroll
      for (int u = 0; u < 8; ++u) {
        const float4* kp = reinterpret_cast<const float4*>(&Kt[jb + u][dbase]);
        float4 kf[8];
#pragma unroll
        for (int w = 0; w < 8; ++w) kf[w] = kp[w];
        float s0 = 0.f, s1 = 0.f, s2 = 0.f, s3 = 0.f;
#pragma unroll
        for (int w = 0; w < 8; ++w) {
          s0 = fmaf(q4[w].x, kf[w].x, s0);
          s1 = fmaf(q4[w].y, kf[w].y, s1);
          s2 = fmaf(q4[w].z, kf[w].z, s2);
          s3 = fmaf(q4[w].w, kf[w].w, s3);
        }
        sarr[u] = fmaf((s0 + s1) + (s2 + s3), 0.17677669529663687f,
                       ((mbits >> u) & 1u) ? 0.f : -1e9f);
      }
      // merge: one rescale per 8 jj
      float smax = fmaxf(fmaxf(fmaxf(sarr[0], sarr[1]), fmaxf(sarr[2], sarr[3])),
                         fmaxf(fmaxf(sarr[4], sarr[5]), fmaxf(sarr[6], sarr[7])));
      float mnew = fmaxf(m, smax);
      float r = __expf(m - mnew);
      m = mnew;
      l *= r;
#pragma unroll
      for (int u = 0; u < 8; ++u) {
        a[u].x *= r; a[u].y *= r; a[u].z *= r; a[u].w *= r;
      }
      // pass 2: exp + PV
#pragma unroll
      for (int u = 0; u < 8; ++u) {
        float p = __expf(sarr[u] - m);
        l += p;
        const float4* vp = reinterpret_cast<const float4*>(&Vt[jb + u][dbase]);
#pragma unroll
        for (int w = 0; w < 8; ++w) {
          float4 vf = vp[w];
          a[w].x = fmaf(p, vf.x, a[w].x);
          a[w].y = fmaf(p, vf.y, a[w].y);
          a[w].z = fmaf(p, vf.z, a[w].z);
          a[w].w = fmaf(p, vf.w, a[w].w);
        }
      }
    }
  }
  {
    float4* pa4 = reinterpret_cast<float4*>(pacc + ((size_t)split * N + i) * 128 + dbase);
#pragma unroll
    for (int u = 0; u < 8; ++u) pa4[u] = a[u];
  }
  {
    float2* p2 = reinterpret_cast<float2*>(pml + (((size_t)split * N + i) * NHEAD + h) * 2);
    *p2 = make_float2(m, l);
  }
}

// combine attention partials across SPLIT_ATT
__global__ __launch_bounds__(256) void k_attn_comb(const float* __restrict__ pacc,
    const float* __restrict__ pml, float* __restrict__ attnout) {
  const int gid = blockIdx.x * 256 + threadIdx.x;
  const int i = gid >> 7, e = gid & 127, h = e >> 5;
  float ms[SPLIT_ATT], ls[SPLIT_ATT];
  float M = -1e30f;
#pragma unroll
  for (int s = 0; s < SPLIT_ATT; ++s) {
    size_t idx = (((size_t)s * N + i) * NHEAD + h) * 2;
    ms[s] = pml[idx]; ls[s] = pml[idx + 1];
    M = fmaxf(M, ms[s]);
  }
  float L = 0.f, o = 0.f;
#pragma unroll
  for (int s = 0; s < SPLIT_ATT; ++s) {
    float w = expf(ms[s] - M);    // dead/masked splits vanish exactly
    L = fmaf(ls[s], w, L);
    o = fmaf(pacc[((size_t)(s * N + i)) * 128 + e], w, o);
  }
  attnout[gid] = o / L;
}

// ------------------------------------------------------------------
// ctx = attnout @ Wo ; cj = ctx @ gate_wb
__global__ __launch_bounds__(128) void k_ctx(const float* __restrict__ att,
    const float* __restrict__ Wo, const float* __restrict__ wb,
    float* __restrict__ ctx, float* __restrict__ cj) {
  __shared__ float xs[8][128];
  __shared__ float hs[8][128];
  const int t = threadIdx.x;
  const int row0 = blockIdx.x * 8;
  {
    const float4* src = reinterpret_cast<const float4*>(att + row0 * 128);
    float4* dst = reinterpret_cast<float4*>(&xs[0][0]);
    for (int idx = t; idx < 256; idx += 128) dst[idx] = src[idx];
  }
  __syncthreads();
  float acc[8] = {0.f,0.f,0.f,0.f,0.f,0.f,0.f,0.f};
  for (int k = 0; k < 128; ++k) {
    float w = Wo[k * 128 + t];
#pragma unroll
    for (int r = 0; r < 8; ++r) acc[r] = fmaf(xs[r][k], w, acc[r]);
  }
  const float wbt = wb[t];
#pragma unroll
  for (int r = 0; r < 8; ++r) {
    ctx[(row0 + r) * 128 + t] = acc[r];
    hs[r][t] = acc[r] * wbt;
  }
  __syncthreads();
  const int wv = t >> 6, lane = t & 63;
  for (int rr = 0; rr < 4; ++rr) {
    int row = wv * 4 + rr;
    float s1 = hs[row][lane] + hs[row][lane + 64];
#pragma unroll
    for (int off = 1; off < 64; off <<= 1) s1 += __shfl_xor(s1, off);
    if (lane == 0) cj[row0 + row] = s1;
  }
}

// ------------------------------------------------------------------
// gate partial (register-tiled GEMM, bitmask build):
//   acc[i,e] = sum_j nmask(i,j) * sigmoid(ti[i]+cj[j]+gb) * ctx[j,e]
__global__ __launch_bounds__(256) void k_gate(const float* __restrict__ ctx,
    const float* __restrict__ cj, const float* __restrict__ ti,
    const unsigned int* __restrict__ bmw, const float* __restrict__ gbp,
    float* __restrict__ pacc, float* __restrict__ pcnt) {
  __shared__ float cs[64][128];
  __shared__ float gtsT[64][65];
  __shared__ float tis[64];
  __shared__ float cntrow[64];
  __shared__ float pcsum[256];
  const int t = threadIdx.x;
  const int itile = blockIdx.x >> 3;
  const int split = blockIdx.x & 7;
  const int ig = t >> 4;
  const int eg = t & 15;
  const int i0 = itile * 64;
  const float gb = gbp[0];
  if (t < 64) { tis[t] = ti[i0 + t]; cntrow[t] = 0.f; }
  float acc[4][8];
#pragma unroll
  for (int r = 0; r < 4; ++r)
#pragma unroll
    for (int c = 0; c < 8; ++c) acc[r][c] = 0.f;
  const int j0beg = split * (N / SPLIT_G);
  const int j0end = j0beg + (N / SPLIT_G);
  for (int j0 = j0beg; j0 < j0end; j0 += 64) {
    __syncthreads();
    {
      const float4* src = reinterpret_cast<const float4*>(ctx + (size_t)j0 * 128);
      float4* dst = reinterpret_cast<float4*>(&cs[0][0]);
#pragma unroll
      for (int u = 0; u < 8; ++u) dst[t + 256 * u] = src[t + 256 * u];
    }
    {  // build gates: row ii = t>>2, 16 bits from bitmask
      const int ii = t >> 2;
      const int qd = t & 3;
      const int jb = qd * 16;
      const int gi = i0 + ii;
      const float tii = tis[ii];
      const unsigned word = bmw[(size_t)gi * 128 + (j0 >> 5) + (qd >> 1)];
      const unsigned mb16 = (word >> ((qd & 1) * 16)) & 0xFFFFu;
      float cnt_loc = 0.f;
      const float4* cjp = reinterpret_cast<const float4*>(cj + j0 + jb);
      float4 cv[4];
#pragma unroll
      for (int u = 0; u < 4; ++u) cv[u] = cjp[u];
      const float cva[16] = {cv[0].x,cv[0].y,cv[0].z,cv[0].w, cv[1].x,cv[1].y,cv[1].z,cv[1].w,
                             cv[2].x,cv[2].y,cv[2].z,cv[2].w, cv[3].x,cv[3].y,cv[3].z,cv[3].w};
#pragma unroll
      for (int w = 0; w < 16; ++w) {
        const int gj = j0 + jb + w;
        const bool live = ((mb16 >> w) & 1u) && (gj != gi);
        float gval = 0.f;
        if (live) {
          gval = __fdividef(1.f, 1.f + __expf(-(tii + cva[w] + gb)));
          cnt_loc += 1.f;
        }
        gtsT[jb + w][ii] = gval;
      }
      pcsum[t] = cnt_loc;
    }
    __syncthreads();
    if (t < 64) {
      cntrow[t] += pcsum[t * 4] + pcsum[t * 4 + 1] + pcsum[t * 4 + 2] + pcsum[t * 4 + 3];
    }
    const int ib = ig * 4;
    const int eb = eg * 8;
    for (int jj = 0; jj < 64; ++jj) {
      const float a0 = gtsT[jj][ib + 0];
      const float a1 = gtsT[jj][ib + 1];
      const float a2 = gtsT[jj][ib + 2];
      const float a3 = gtsT[jj][ib + 3];
      const float4 b0 = *reinterpret_cast<const float4*>(&cs[jj][eb]);
      const float4 b1 = *reinterpret_cast<const float4*>(&cs[jj][eb + 4]);
      const float bv[8] = {b0.x, b0.y, b0.z, b0.w, b1.x, b1.y, b1.z, b1.w};
#pragma unroll
      for (int c = 0; c < 8; ++c) {
        acc[0][c] = fmaf(a0, bv[c], acc[0][c]);
        acc[1][c] = fmaf(a1, bv[c], acc[1][c]);
        acc[2][c] = fmaf(a2, bv[c], acc[2][c]);
        acc[3][c] = fmaf(a3, bv[c], acc[3][c]);
      }
    }
  }
#pragma unroll
  for (int r = 0; r < 4; ++r) {
    float* pa = pacc + ((size_t)split * N + i0 + ig * 4 + r) * 128 + eg * 8;
    float4 o0; o0.x = acc[r][0]; o0.y = acc[r][1]; o0.z = acc[r][2]; o0.w = acc[r][3];
    float4 o1; o1.x = acc[r][4]; o1.y = acc[r][5]; o1.z = acc[r][6]; o1.w = acc[r][7];
    reinterpret_cast<float4*>(pa)[0] = o0;
    reinterpret_cast<float4*>(pa)[1] = o1;
  }
  if (t < 64) pcnt[(size_t)split * N + i0 + t] = cntrow[t];
}

// gate combine + updated + generational memory retrieval
__global__ __launch_bounds__(256) void k_gcomb(const float* __restrict__ GA,
    const float* __restrict__ GC, const float* __restrict__ emb,
    const float* __restrict__ mb, float* __restrict__ upd) {
  __shared__ float mbs[10][128];
  __shared__ float us[2][128];
  const int t = threadIdx.x;
  for (int idx = t; idx < 1280; idx += 256) mbs[idx / 128][idx & 127] = mb[idx];
  const int rs = t >> 7, e = t & 127;
  const int i = blockIdx.x * 2 + rs;
  float a = 0.f;
#pragma unroll
  for (int s = 0; s < SPLIT_G; ++s) a += GA[((size_t)(s * N + i)) * 128 + e];
  float c = 0.f;
#pragma unroll
  for (int s = 0; s < SPLIT_G; ++s) c += GC[s * N + i];
  float comb = a / fmaxf(c, 1.f);
  float u = emb[(size_t)i * 128 + e] + 0.2f * ((c > 0.f) ? comb : 0.f);
  us[rs][e] = u;
  __syncthreads();
  const int wv = t >> 6, lane = t & 63;
  if (wv < 2) {
    const int i2 = blockIdx.x * 2 + wv;
    float u0 = us[wv][lane], u1 = us[wv][lane + 64];
    float sc[10];
#pragma unroll
    for (int g = 0; g < 10; ++g) {
      float p = u0 * mbs[g][lane] + u1 * mbs[g][lane + 64];
#pragma unroll
      for (int off = 1; off < 64; off <<= 1) p += __shfl_xor(p, off);
      sc[g] = p * 0.08838834764831845f;
    }
    float mx = sc[0];
#pragma unroll
    for (int g = 1; g < 10; ++g) mx = fmaxf(mx, sc[g]);
    float sum = 0.f;
#pragma unroll
    for (int g = 0; g < 10; ++g) { sc[g] = expf(sc[g] - mx); sum += sc[g]; }
    float inv = 1.f / sum;
    float anc0 = 0.f, anc1 = 0.f;
#pragma unroll
    for (int g = 0; g < 10; ++g) {
      float pg = sc[g] * inv;
      anc0 = fmaf(pg, mbs[g][lane], anc0);
      anc1 = fmaf(pg, mbs[g][lane + 64], anc1);
    }
    upd[(size_t)i2 * 128 + lane]      = 0.9f * u0 + 0.1f * anc0;
    upd[(size_t)i2 * 128 + lane + 64] = 0.9f * u1 + 0.1f * anc1;
  }
}

// ------------------------------------------------------------------
// dec1: D = relu(LN(UPD[N,128] @ W[128,512] + b))
__global__ __launch_bounds__(512) void k_dec1(const float* __restrict__ X,
    const float* __restrict__ W, const float* __restrict__ b,
    const float* __restrict__ g, const float* __restrict__ be,
    float* __restrict__ out) {
  __shared__ float xs[8][128];
  __shared__ float hs[8][512];
  const int t = threadIdx.x;
  const int row0 = blockIdx.x * 8;
  if (t < 256) {
    const float4* src = reinterpret_cast<const float4*>(X + row0 * 128);
    float4* dst = reinterpret_cast<float4*>(&xs[0][0]);
    dst[t] = src[t];
  }
  __syncthreads();
  float acc[8] = {0.f,0.f,0.f,0.f,0.f,0.f,0.f,0.f};
  for (int k = 0; k < 128; ++k) {
    float w = W[k * 512 + t];
#pragma unroll
    for (int r = 0; r < 8; ++r) acc[r] = fmaf(xs[r][k], w, acc[r]);
  }
  const float bb = b[t];
#pragma unroll
  for (int r = 0; r < 8; ++r) hs[r][t] = acc[r] + bb;
  __syncthreads();
  const int wv = t >> 6, lane = t & 63;
  float v0[8];
  float s1 = 0.f, s2 = 0.f;
#pragma unroll
  for (int kk = 0; kk < 8; ++kk) {
    float x = hs[wv][lane + 64 * kk];
    v0[kk] = x; s1 += x; s2 += x * x;
  }
#pragma unroll
  for (int off = 1; off < 64; off <<= 1) { s1 += __shfl_xor(s1, off); s2 += __shfl_xor(s2, off); }
  const float mean = s1 * (1.f / 512.f);
  const float var = s2 * (1.f / 512.f) - mean * mean;
  const float rstd = rsqrtf(var + 1e-5f);
#pragma unroll
  for (int kk = 0; kk < 8; ++kk) {
    int c = lane + 64 * kk;
    float y = g[c] * (v0[kk] - mean) * rstd + be[c];
    out[(row0 + wv) * 512 + c] = fmaxf(y, 0.f);
  }
}

// dec2: out = D[N,512] @ W[512,256] + b
__global__ __launch_bounds__(256) void k_dec2(const float* __restrict__ X,
    const float* __restrict__ W, const float* __restrict__ b, float* __restrict__ out) {
  __shared__ float xs[8][512];
  const int t = threadIdx.x;
  const int row0 = blockIdx.x * 8;
  {
    const float4* src = reinterpret_cast<const float4*>(X + row0 * 512);
    float4* dst = reinterpret_cast<float4*>(&xs[0][0]);
    for (int idx = t; idx < 1024; idx += 256) dst[idx] = src[idx];
  }
  __syncthreads();
  float acc[8] = {0.f,0.f,0.f,0.f,0.f,0.f,0.f,0.f};
  for (int k = 0; k < 512; ++k) {
    float w = W[k * 256 + t];
#pragma unroll
    for (int r = 0; r < 8; ++r) acc[r] = fmaf(xs[r][k], w, acc[r]);
  }
  const float bb = b[t];
#pragma unroll
  for (int r = 0; r < 8; ++r) out[(row0 + r) * 256 + t] = acc[r] + bb;
}

// ------------------------------------------------------------------
extern "C" void kernel_launch(void* const* d_in, const int* in_sizes, int n_in,
                              void* d_out, int out_size, void* d_ws, size_t ws_size,
                              hipStream_t stream) {
  const float* lora   = (const float*)d_in[0];
  const float* temps  = (const float*)d_in[1];
  const int*   adj    = (const int*)d_in[2];
  const float* mb     = (const float*)d_in[3];
  const float* enc_W1 = (const float*)d_in[4];
  const float* enc_b1 = (const float*)d_in[5];
  const float* enc_g1 = (const float*)d_in[6];
  const float* enc_be1= (const float*)d_in[7];
  const float* enc_W2 = (const float*)d_in[8];
  const float* enc_b2 = (const float*)d_in[9];
  const float* enc_g2 = (const float*)d_in[10];
  const float* enc_be2= (const float*)d_in[11];
  const float* temp_W = (const float*)d_in[12];
  const float* temp_b = (const float*)d_in[13];
  const float* Wq     = (const float*)d_in[14];
  const float* Wk     = (const float*)d_in[15];
  const float* Wv     = (const float*)d_in[16];
  const float* Wo     = (const float*)d_in[17];
  const float* g_wa   = (const float*)d_in[18];
  const float* g_wb   = (const float*)d_in[19];
  const float* g_b    = (const float*)d_in[20];
  const float* dec_W1 = (const float*)d_in[21];
  const float* dec_b1 = (const float*)d_in[22];
  const float* dec_g1 = (const float*)d_in[23];
  const float* dec_be1= (const float*)d_in[24];
  const float* dec_W2 = (const float*)d_in[25];
  const float* dec_b2 = (const float*)d_in[26];

  float* ws = (float*)d_ws;
  float* H1  = ws;                      // N*512 (reused as DEC later)
  float* EMB = H1 + (size_t)N * 512;    // N*128
  float* Q   = EMB + (size_t)N * 128;
  float* K   = Q + (size_t)N * 128;
  float* V   = K + (size_t)N * 128;
  float* ATT = V + (size_t)N * 128;     // reused as UPD later
  float* CTX = ATT + (size_t)N * 128;
  float* TI  = CTX + (size_t)N * 128;   // N
  float* CJ  = TI + N;                  // N
  float* PA  = CJ + N;                  // 8*N*128 (reused as GA)
  float* PML = PA + (size_t)8 * N * 128;  // 8*N*NHEAD*2 (reused as GC, 8*N)
  unsigned int* BMW = (unsigned int*)(PML + (size_t)8 * N * NHEAD * 2);  // N*128 words
  float* UPD = ATT;
  float* GA  = PA;
  float* GC  = PML;
  float* DEC = H1;

  k_bm<<<512, 256, 0, stream>>>(adj, BMW);
  k_enc1<<<N / 8, 512, 0, stream>>>(lora, enc_W1, enc_b1, enc_g1, enc_be1, H1);
  k_enc2<<<N / 8, 128, 0, stream>>>(H1, enc_W2, enc_b2, enc_g2, enc_be2, EMB);
  k_ti<<<N / 64, 256, 0, stream>>>(temps, temp_W, temp_b, g_wa, TI);
  k_qkv<<<N / 16, 512, 0, stream>>>(EMB, Wq, Wk, Wv, Q, K, V);
  k_attn<<<(N / 64) * SPLIT_ATT, 256, 0, stream>>>(Q, K, V, BMW, PA, PML);
  k_attn_comb<<<(N * 128) / 256, 256, 0, stream>>>(PA, PML, ATT);
  k_ctx<<<N / 8, 128, 0, stream>>>(ATT, Wo, g_wb, CTX, CJ);
  k_gate<<<(N / 64) * SPLIT_G, 256, 0, stream>>>(CTX, CJ, TI, BMW, g_b, GA, GC);
  k_gcomb<<<N / 2, 256, 0, stream>>>(GA, GC, EMB, mb, UPD);
  k_dec1<<<N / 8, 512, 0, stream>>>(UPD, dec_W1, dec_b1, dec_g1, dec_be1, DEC);
  k_dec2<<<N / 8, 256, 0, stream>>>(DEC, dec_W2, dec_b2, (float*)d_out);
}

// Round 8
// 625.690 us; speedup vs baseline: 1.1454x; 1.1454x over previous
//
#include <hip/hip_runtime.h>
#include <math.h>

#define N 4096
#define NHEAD 4
#define SPLIT_ATT 16
#define SPLIT_G 8

// ------------------------------------------------------------------
// bitmask pre-pass: bmw[i][w] bit j = (adj[i][w*32+j] != 0)
__global__ __launch_bounds__(256) void k_bm(const int* __restrict__ adj,
    unsigned int* __restrict__ bmw) {
  const int lane = threadIdx.x & 63;
  const int wid = threadIdx.x >> 6;
  const long total = (long)N * N / 64;
  long g = (long)blockIdx.x * 4 + wid;
  const long stride = (long)gridDim.x * 4;
  for (; g < total; g += stride) {
    int e = adj[g * 64 + lane];
    unsigned long long mask = __ballot(e != 0);
    if (lane == 0)  bmw[g * 2]     = (unsigned int)(mask & 0xFFFFFFFFull);
    if (lane == 32) bmw[g * 2 + 1] = (unsigned int)(mask >> 32);
  }
}

// ------------------------------------------------------------------
// enc1: H1 = relu(LN(X[N,256] @ W[256,512] + b))
// 256 thr, 8 rows/block, thread = cols (t, t+256); float4-k.
__global__ __launch_bounds__(256) void k_enc1(const float* __restrict__ X,
    const float* __restrict__ W, const float* __restrict__ b,
    const float* __restrict__ g, const float* __restrict__ be,
    float* __restrict__ out) {
  __shared__ float xs[8][256];
  __shared__ float hs[8][512];
  const int t = threadIdx.x;
  const int row0 = blockIdx.x * 8;
  {
    const float4* src = reinterpret_cast<const float4*>(X + row0 * 256);
    float4* dst = reinterpret_cast<float4*>(&xs[0][0]);
    dst[t] = src[t]; dst[t + 256] = src[t + 256];
  }
  __syncthreads();
  float acc0[8], acc1[8];
#pragma unroll
  for (int r = 0; r < 8; ++r) { acc0[r] = 0.f; acc1[r] = 0.f; }
  for (int k4 = 0; k4 < 64; ++k4) {
    const int k = k4 * 4;
    const float w00 = W[(k + 0) * 512 + t];
    const float w01 = W[(k + 1) * 512 + t];
    const float w02 = W[(k + 2) * 512 + t];
    const float w03 = W[(k + 3) * 512 + t];
    const float w10 = W[(k + 0) * 512 + t + 256];
    const float w11 = W[(k + 1) * 512 + t + 256];
    const float w12 = W[(k + 2) * 512 + t + 256];
    const float w13 = W[(k + 3) * 512 + t + 256];
#pragma unroll
    for (int r = 0; r < 8; ++r) {
      const float4 xv = *reinterpret_cast<const float4*>(&xs[r][k]);
      acc0[r] = fmaf(xv.x, w00, fmaf(xv.y, w01, fmaf(xv.z, w02, fmaf(xv.w, w03, acc0[r]))));
      acc1[r] = fmaf(xv.x, w10, fmaf(xv.y, w11, fmaf(xv.z, w12, fmaf(xv.w, w13, acc1[r]))));
    }
  }
  const float b0 = b[t], b1 = b[t + 256];
#pragma unroll
  for (int r = 0; r < 8; ++r) { hs[r][t] = acc0[r] + b0; hs[r][t + 256] = acc1[r] + b1; }
  __syncthreads();
  const int wv = t >> 6, lane = t & 63;
  for (int rr = 0; rr < 2; ++rr) {
    const int row = wv * 2 + rr;
    float v0[8];
    float s1 = 0.f, s2 = 0.f;
#pragma unroll
    for (int kk = 0; kk < 8; ++kk) {
      float x = hs[row][lane + 64 * kk];
      v0[kk] = x; s1 += x; s2 += x * x;
    }
#pragma unroll
    for (int off = 1; off < 64; off <<= 1) { s1 += __shfl_xor(s1, off); s2 += __shfl_xor(s2, off); }
    const float mean = s1 * (1.f / 512.f);
    const float rstd = rsqrtf(s2 * (1.f / 512.f) - mean * mean + 1e-5f);
#pragma unroll
    for (int kk = 0; kk < 8; ++kk) {
      int c = lane + 64 * kk;
      float y = g[c] * (v0[kk] - mean) * rstd + be[c];
      out[(row0 + row) * 512 + c] = fmaxf(y, 0.f);
    }
  }
}

// ------------------------------------------------------------------
// enc2: EMB = LN(H1[N,512] @ W[512,128] + b)
// 256 thr, 8 rows/block: col = t&127, rowgrp = t>>7 (2 x 4 rows); float4-k.
__global__ __launch_bounds__(256) void k_enc2(const float* __restrict__ X,
    const float* __restrict__ W, const float* __restrict__ b,
    const float* __restrict__ g, const float* __restrict__ be,
    float* __restrict__ out) {
  __shared__ float xs[8][512];
  __shared__ float hs[8][128];
  const int t = threadIdx.x;
  const int row0 = blockIdx.x * 8;
  {
    const float4* src = reinterpret_cast<const float4*>(X + row0 * 512);
    float4* dst = reinterpret_cast<float4*>(&xs[0][0]);
#pragma unroll
    for (int u = 0; u < 4; ++u) dst[t + 256 * u] = src[t + 256 * u];
  }
  __syncthreads();
  const int col = t & 127;
  const int rg = t >> 7;        // 0/1 -> rows rg*4..rg*4+3
  float acc[4] = {0.f,0.f,0.f,0.f};
  for (int k4 = 0; k4 < 128; ++k4) {
    const int k = k4 * 4;
    const float w0 = W[(k + 0) * 128 + col];
    const float w1 = W[(k + 1) * 128 + col];
    const float w2 = W[(k + 2) * 128 + col];
    const float w3 = W[(k + 3) * 128 + col];
#pragma unroll
    for (int r = 0; r < 4; ++r) {
      const float4 xv = *reinterpret_cast<const float4*>(&xs[rg * 4 + r][k]);
      acc[r] = fmaf(xv.x, w0, fmaf(xv.y, w1, fmaf(xv.z, w2, fmaf(xv.w, w3, acc[r]))));
    }
  }
  const float bb = b[col];
#pragma unroll
  for (int r = 0; r < 4; ++r) hs[rg * 4 + r][col] = acc[r] + bb;
  __syncthreads();
  const int wv = t >> 6, lane = t & 63;
  for (int rr = 0; rr < 2; ++rr) {
    const int row = wv * 2 + rr;
    float a0 = hs[row][lane], a1 = hs[row][lane + 64];
    float s1 = a0 + a1, s2 = a0 * a0 + a1 * a1;
#pragma unroll
    for (int off = 1; off < 64; off <<= 1) { s1 += __shfl_xor(s1, off); s2 += __shfl_xor(s2, off); }
    float mean = s1 * (1.f / 128.f);
    float rstd = rsqrtf(s2 * (1.f / 128.f) - mean * mean + 1e-5f);
    out[(row0 + row) * 128 + lane]      = g[lane] * (a0 - mean) * rstd + be[lane];
    out[(row0 + row) * 128 + lane + 64] = g[lane + 64] * (a1 - mean) * rstd + be[lane + 64];
  }
}

// ------------------------------------------------------------------
// qkv: 512 thr, 16 rows/block, grp(4) x 4 rows; float4-k.
__global__ __launch_bounds__(512) void k_qkv(const float* __restrict__ emb,
    const float* __restrict__ Wq, const float* __restrict__ Wk, const float* __restrict__ Wv,
    float* __restrict__ q, float* __restrict__ k, float* __restrict__ v) {
  __shared__ float xs[16][128];
  const int t = threadIdx.x;
  const int col = t & 127;
  const int grp = t >> 7;
  const int row0 = blockIdx.x * 16;
  {
    const float4* src = reinterpret_cast<const float4*>(emb + row0 * 128);
    float4* dst = reinterpret_cast<float4*>(&xs[0][0]);
    dst[t] = src[t];
  }
  __syncthreads();
  float aq[4] = {0.f,0.f,0.f,0.f};
  float ak[4] = {0.f,0.f,0.f,0.f};
  float av[4] = {0.f,0.f,0.f,0.f};
  for (int k4 = 0; k4 < 32; ++k4) {
    const int kk = k4 * 4;
    float wq0 = Wq[(kk+0)*128+col], wq1 = Wq[(kk+1)*128+col], wq2 = Wq[(kk+2)*128+col], wq3 = Wq[(kk+3)*128+col];
    float wk0 = Wk[(kk+0)*128+col], wk1 = Wk[(kk+1)*128+col], wk2 = Wk[(kk+2)*128+col], wk3 = Wk[(kk+3)*128+col];
    float wv0 = Wv[(kk+0)*128+col], wv1 = Wv[(kk+1)*128+col], wv2 = Wv[(kk+2)*128+col], wv3 = Wv[(kk+3)*128+col];
#pragma unroll
    for (int r = 0; r < 4; ++r) {
      const float4 xv = *reinterpret_cast<const float4*>(&xs[grp * 4 + r][kk]);
      aq[r] = fmaf(xv.x, wq0, fmaf(xv.y, wq1, fmaf(xv.z, wq2, fmaf(xv.w, wq3, aq[r]))));
      ak[r] = fmaf(xv.x, wk0, fmaf(xv.y, wk1, fmaf(xv.z, wk2, fmaf(xv.w, wk3, ak[r]))));
      av[r] = fmaf(xv.x, wv0, fmaf(xv.y, wv1, fmaf(xv.z, wv2, fmaf(xv.w, wv3, av[r]))));
    }
  }
#pragma unroll
  for (int r = 0; r < 4; ++r) {
    const int row = row0 + grp * 4 + r;
    q[row * 128 + col] = aq[r];
    k[row * 128 + col] = ak[r];
    v[row * 128 + col] = av[r];
  }
}

// ------------------------------------------------------------------
// ti[i] = sum_e tanh(temps[i,:] @ tW[:,e] + tb[e]) * wa[e]
__global__ __launch_bounds__(256) void k_ti(const float* __restrict__ temps,
    const float* __restrict__ tW, const float* __restrict__ tb,
    const float* __restrict__ wa, float* __restrict__ ti_out) {
  __shared__ float tws[1280];
  __shared__ float tbs[128], was[128];
  const int t = threadIdx.x;
  for (int idx = t; idx < 1280; idx += 256) tws[idx] = tW[idx];
  if (t < 128) { tbs[t] = tb[t]; was[t] = wa[t]; }
  __syncthreads();
  const int qi = t & 3;
  const int li = t >> 2;
  const int i = blockIdx.x * 64 + li;
  float tp[10];
#pragma unroll
  for (int c = 0; c < 10; ++c) tp[c] = temps[i * 10 + c];
  float acc = 0.f;
  const int e0 = qi * 32;
  for (int e = e0; e < e0 + 32; ++e) {
    float s = tbs[e];
#pragma unroll
    for (int c = 0; c < 10; ++c) s = fmaf(tp[c], tws[c * 128 + e], s);
    float th = 1.f - 2.f * __fdividef(1.f, __expf(2.f * s) + 1.f);
    acc = fmaf(th, was[e], acc);
  }
  acc += __shfl_xor(acc, 1);
  acc += __shfl_xor(acc, 2);
  if (qi == 0) ti_out[i] = acc;
}

// ------------------------------------------------------------------
// flash attention v6: branchless 2-pass sub-tile softmax + bitmask.
// 256 thr = 4 waves: wave = head, lane = i-row (64-row tile).
// j-tile 32 (32KB LDS), SPLIT_ATT=16 -> grid 1024 = 4 blocks/CU,
// launch_bounds(256,4) -> 4 waves/SIMD. Wave-coherent rescale skip.
__global__ __launch_bounds__(256, 4) void k_attn(const float* __restrict__ q,
    const float* __restrict__ kk, const float* __restrict__ vv,
    const unsigned int* __restrict__ bmw,
    float* __restrict__ pacc, float* __restrict__ pml) {
  __shared__ float Kt[32][128];
  __shared__ float Vt[32][128];
  const int t = threadIdx.x;
  const int itile = blockIdx.x / SPLIT_ATT;
  const int split = blockIdx.x % SPLIT_ATT;
  const int h = t >> 6;
  const int row = t & 63;
  const int i = itile * 64 + row;
  const int dbase = h * 32;
  float4 q4[8];
  {
    const float4* qp = reinterpret_cast<const float4*>(q + (size_t)i * 128 + dbase);
#pragma unroll
    for (int u = 0; u < 8; ++u) q4[u] = qp[u];
  }
  float m = -1e30f, l = 0.f;
  float4 a[8];
#pragma unroll
  for (int u = 0; u < 8; ++u) a[u] = make_float4(0.f, 0.f, 0.f, 0.f);
  const int jrange = N / SPLIT_ATT;               // 256
  const int j0beg = split * jrange;
  const int j0end = j0beg + jrange;
  for (int j0 = j0beg; j0 < j0end; j0 += 32) {
    __syncthreads();
    {
      const float4* ks = reinterpret_cast<const float4*>(kk + (size_t)j0 * 128);
      const float4* vs = reinterpret_cast<const float4*>(vv + (size_t)j0 * 128);
      float4* kd = reinterpret_cast<float4*>(&Kt[0][0]);
      float4* vd = reinterpret_cast<float4*>(&Vt[0][0]);
#pragma unroll
      for (int u = 0; u < 4; ++u) { kd[t + 256 * u] = ks[t + 256 * u]; vd[t + 256 * u] = vs[t + 256 * u]; }
    }
    const unsigned mword = bmw[(size_t)i * 128 + (j0 >> 5)];
    const int eyeoff = i - j0;
    __syncthreads();
    for (int sub = 0; sub < 4; ++sub) {
      const int jb = sub * 8;
      unsigned mbits = (mword >> jb) & 0xFFu;
      if (((unsigned)(eyeoff - jb)) < 8u) mbits |= (1u << (eyeoff - jb));
      float sarr[8];
#pragma unroll
      for (int u = 0; u < 8; ++u) {
        const float4* kp = reinterpret_cast<const float4*>(&Kt[jb + u][dbase]);
        float4 kf[8];
#pragma unroll
        for (int x = 0; x < 8; ++x) kf[x] = kp[x];
        float s0 = 0.f, s1 = 0.f, s2 = 0.f, s3 = 0.f;
#pragma unroll
        for (int x = 0; x < 8; ++x) {
          s0 = fmaf(q4[x].x, kf[x].x, s0);
          s1 = fmaf(q4[x].y, kf[x].y, s1);
          s2 = fmaf(q4[x].z, kf[x].z, s2);
          s3 = fmaf(q4[x].w, kf[x].w, s3);
        }
        sarr[u] = fmaf((s0 + s1) + (s2 + s3), 0.17677669529663687f,
                       ((mbits >> u) & 1u) ? 0.f : -1e9f);
      }
      float smax = fmaxf(fmaxf(fmaxf(sarr[0], sarr[1]), fmaxf(sarr[2], sarr[3])),
                         fmaxf(fmaxf(sarr[4], sarr[5]), fmaxf(sarr[6], sarr[7])));
      if (__any(smax > m)) {            // wave-coherent: skip rescale when no lane's max moved
        float mnew = fmaxf(m, smax);
        float r = __expf(m - mnew);
        m = mnew;
        l *= r;
#pragma unroll
        for (int u = 0; u < 8; ++u) {
          a[u].x *= r; a[u].y *= r; a[u].z *= r; a[u].w *= r;
        }
      }
#pragma unroll
      for (int u = 0; u < 8; ++u) {
        float p = __expf(sarr[u] - m);
        l += p;
        const float4* vp = reinterpret_cast<const float4*>(&Vt[jb + u][dbase]);
#pragma unroll
        for (int x = 0; x < 8; ++x) {
          float4 vf = vp[x];
          a[x].x = fmaf(p, vf.x, a[x].x);
          a[x].y = fmaf(p, vf.y, a[x].y);
          a[x].z = fmaf(p, vf.z, a[x].z);
          a[x].w = fmaf(p, vf.w, a[x].w);
        }
      }
    }
  }
  {
    float4* pa4 = reinterpret_cast<float4*>(pacc + ((size_t)split * N + i) * 128 + dbase);
#pragma unroll
    for (int u = 0; u < 8; ++u) pa4[u] = a[u];
  }
  {
    float2* p2 = reinterpret_cast<float2*>(pml + (((size_t)split * N + i) * NHEAD + h) * 2);
    *p2 = make_float2(m, l);
  }
}

// combine attention partials across SPLIT_ATT
__global__ __launch_bounds__(256) void k_attn_comb(const float* __restrict__ pacc,
    const float* __restrict__ pml, float* __restrict__ attnout) {
  const int gid = blockIdx.x * 256 + threadIdx.x;
  const int i = gid >> 7, e = gid & 127, h = e >> 5;
  float ms[SPLIT_ATT], ls[SPLIT_ATT];
  float M = -1e30f;
#pragma unroll
  for (int s = 0; s < SPLIT_ATT; ++s) {
    size_t idx = (((size_t)s * N + i) * NHEAD + h) * 2;
    ms[s] = pml[idx]; ls[s] = pml[idx + 1];
    M = fmaxf(M, ms[s]);
  }
  float L = 0.f, o = 0.f;
#pragma unroll
  for (int s = 0; s < SPLIT_ATT; ++s) {
    float w = expf(ms[s] - M);    // dead/masked splits vanish exactly
    L = fmaf(ls[s], w, L);
    o = fmaf(pacc[((size_t)(s * N + i)) * 128 + e], w, o);
  }
  attnout[gid] = o / L;
}

// ------------------------------------------------------------------
// ctx = attnout @ Wo ; cj = ctx @ gate_wb ; 16 rows/block, float4-k
__global__ __launch_bounds__(512) void k_ctx(const float* __restrict__ att,
    const float* __restrict__ Wo, const float* __restrict__ wb,
    float* __restrict__ ctx, float* __restrict__ cj) {
  __shared__ float xs[16][128];
  __shared__ float hs[16][128];
  const int t = threadIdx.x;
  const int row0 = blockIdx.x * 16;
  {
    const float4* src = reinterpret_cast<const float4*>(att + row0 * 128);
    float4* dst = reinterpret_cast<float4*>(&xs[0][0]);
    dst[t] = src[t];
  }
  __syncthreads();
  const int col = t & 127;
  const int grp = t >> 7;
  float acc[4] = {0.f,0.f,0.f,0.f};
  for (int k4 = 0; k4 < 32; ++k4) {
    const int k = k4 * 4;
    const float w0 = Wo[(k + 0) * 128 + col];
    const float w1 = Wo[(k + 1) * 128 + col];
    const float w2 = Wo[(k + 2) * 128 + col];
    const float w3 = Wo[(k + 3) * 128 + col];
#pragma unroll
    for (int r = 0; r < 4; ++r) {
      const float4 xv = *reinterpret_cast<const float4*>(&xs[grp * 4 + r][k]);
      acc[r] = fmaf(xv.x, w0, fmaf(xv.y, w1, fmaf(xv.z, w2, fmaf(xv.w, w3, acc[r]))));
    }
  }
#pragma unroll
  for (int r = 0; r < 4; ++r) {
    ctx[(row0 + grp * 4 + r) * 128 + col] = acc[r];
    hs[grp * 4 + r][col] = acc[r];
  }
  __syncthreads();
  const int wv = t >> 6, lane = t & 63;
  const float wb0 = wb[lane], wb1 = wb[lane + 64];
  for (int rr = 0; rr < 2; ++rr) {
    const int row = wv * 2 + rr;
    float s1 = hs[row][lane] * wb0 + hs[row][lane + 64] * wb1;
#pragma unroll
    for (int off = 1; off < 64; off <<= 1) s1 += __shfl_xor(s1, off);
    if (lane == 0) cj[row0 + row] = s1;
  }
}

// ------------------------------------------------------------------
// gate partial (register-tiled GEMM, bitmask build)
__global__ __launch_bounds__(256) void k_gate(const float* __restrict__ ctx,
    const float* __restrict__ cj, const float* __restrict__ ti,
    const unsigned int* __restrict__ bmw, const float* __restrict__ gbp,
    float* __restrict__ pacc, float* __restrict__ pcnt) {
  __shared__ float cs[64][128];
  __shared__ float gtsT[64][65];
  __shared__ float tis[64];
  __shared__ float cntrow[64];
  __shared__ float pcsum[256];
  const int t = threadIdx.x;
  const int itile = blockIdx.x >> 3;
  const int split = blockIdx.x & 7;
  const int ig = t >> 4;
  const int eg = t & 15;
  const int i0 = itile * 64;
  const float gb = gbp[0];
  if (t < 64) { tis[t] = ti[i0 + t]; cntrow[t] = 0.f; }
  float acc[4][8];
#pragma unroll
  for (int r = 0; r < 4; ++r)
#pragma unroll
    for (int c = 0; c < 8; ++c) acc[r][c] = 0.f;
  const int j0beg = split * (N / SPLIT_G);
  const int j0end = j0beg + (N / SPLIT_G);
  for (int j0 = j0beg; j0 < j0end; j0 += 64) {
    __syncthreads();
    {
      const float4* src = reinterpret_cast<const float4*>(ctx + (size_t)j0 * 128);
      float4* dst = reinterpret_cast<float4*>(&cs[0][0]);
#pragma unroll
      for (int u = 0; u < 8; ++u) dst[t + 256 * u] = src[t + 256 * u];
    }
    {
      const int ii = t >> 2;
      const int qd = t & 3;
      const int jb = qd * 16;
      const int gi = i0 + ii;
      const float tii = tis[ii];
      const unsigned word = bmw[(size_t)gi * 128 + (j0 >> 5) + (qd >> 1)];
      const unsigned mb16 = (word >> ((qd & 1) * 16)) & 0xFFFFu;
      float cnt_loc = 0.f;
      const float4* cjp = reinterpret_cast<const float4*>(cj + j0 + jb);
      float4 cv[4];
#pragma unroll
      for (int u = 0; u < 4; ++u) cv[u] = cjp[u];
      const float cva[16] = {cv[0].x,cv[0].y,cv[0].z,cv[0].w, cv[1].x,cv[1].y,cv[1].z,cv[1].w,
                             cv[2].x,cv[2].y,cv[2].z,cv[2].w, cv[3].x,cv[3].y,cv[3].z,cv[3].w};
#pragma unroll
      for (int w = 0; w < 16; ++w) {
        const int gj = j0 + jb + w;
        const bool live = ((mb16 >> w) & 1u) && (gj != gi);
        float gval = 0.f;
        if (live) {
          gval = __fdividef(1.f, 1.f + __expf(-(tii + cva[w] + gb)));
          cnt_loc += 1.f;
        }
        gtsT[jb + w][ii] = gval;
      }
      pcsum[t] = cnt_loc;
    }
    __syncthreads();
    if (t < 64) {
      cntrow[t] += pcsum[t * 4] + pcsum[t * 4 + 1] + pcsum[t * 4 + 2] + pcsum[t * 4 + 3];
    }
    const int ib = ig * 4;
    const int eb = eg * 8;
    for (int jj = 0; jj < 64; ++jj) {
      const float a0 = gtsT[jj][ib + 0];
      const float a1 = gtsT[jj][ib + 1];
      const float a2 = gtsT[jj][ib + 2];
      const float a3 = gtsT[jj][ib + 3];
      const float4 b0 = *reinterpret_cast<const float4*>(&cs[jj][eb]);
      const float4 b1 = *reinterpret_cast<const float4*>(&cs[jj][eb + 4]);
      const float bv[8] = {b0.x, b0.y, b0.z, b0.w, b1.x, b1.y, b1.z, b1.w};
#pragma unroll
      for (int c = 0; c < 8; ++c) {
        acc[0][c] = fmaf(a0, bv[c], acc[0][c]);
        acc[1][c] = fmaf(a1, bv[c], acc[1][c]);
        acc[2][c] = fmaf(a2, bv[c], acc[2][c]);
        acc[3][c] = fmaf(a3, bv[c], acc[3][c]);
      }
    }
  }
#pragma unroll
  for (int r = 0; r < 4; ++r) {
    float* pa = pacc + ((size_t)split * N + i0 + ig * 4 + r) * 128 + eg * 8;
    float4 o0; o0.x = acc[r][0]; o0.y = acc[r][1]; o0.z = acc[r][2]; o0.w = acc[r][3];
    float4 o1; o1.x = acc[r][4]; o1.y = acc[r][5]; o1.z = acc[r][6]; o1.w = acc[r][7];
    reinterpret_cast<float4*>(pa)[0] = o0;
    reinterpret_cast<float4*>(pa)[1] = o1;
  }
  if (t < 64) pcnt[(size_t)split * N + i0 + t] = cntrow[t];
}

// gate combine + updated + generational memory retrieval
__global__ __launch_bounds__(256) void k_gcomb(const float* __restrict__ GA,
    const float* __restrict__ GC, const float* __restrict__ emb,
    const float* __restrict__ mb, float* __restrict__ upd) {
  __shared__ float mbs[10][128];
  __shared__ float us[2][128];
  const int t = threadIdx.x;
  for (int idx = t; idx < 1280; idx += 256) mbs[idx / 128][idx & 127] = mb[idx];
  const int rs = t >> 7, e = t & 127;
  const int i = blockIdx.x * 2 + rs;
  float a = 0.f;
#pragma unroll
  for (int s = 0; s < SPLIT_G; ++s) a += GA[((size_t)(s * N + i)) * 128 + e];
  float c = 0.f;
#pragma unroll
  for (int s = 0; s < SPLIT_G; ++s) c += GC[s * N + i];
  float comb = a / fmaxf(c, 1.f);
  float u = emb[(size_t)i * 128 + e] + 0.2f * ((c > 0.f) ? comb : 0.f);
  us[rs][e] = u;
  __syncthreads();
  const int wv = t >> 6, lane = t & 63;
  if (wv < 2) {
    const int i2 = blockIdx.x * 2 + wv;
    float u0 = us[wv][lane], u1 = us[wv][lane + 64];
    float sc[10];
#pragma unroll
    for (int g = 0; g < 10; ++g) {
      float p = u0 * mbs[g][lane] + u1 * mbs[g][lane + 64];
#pragma unroll
      for (int off = 1; off < 64; off <<= 1) p += __shfl_xor(p, off);
      sc[g] = p * 0.08838834764831845f;
    }
    float mx = sc[0];
#pragma unroll
    for (int g = 1; g < 10; ++g) mx = fmaxf(mx, sc[g]);
    float sum = 0.f;
#pragma unroll
    for (int g = 0; g < 10; ++g) { sc[g] = expf(sc[g] - mx); sum += sc[g]; }
    float inv = 1.f / sum;
    float anc0 = 0.f, anc1 = 0.f;
#pragma unroll
    for (int g = 0; g < 10; ++g) {
      float pg = sc[g] * inv;
      anc0 = fmaf(pg, mbs[g][lane], anc0);
      anc1 = fmaf(pg, mbs[g][lane + 64], anc1);
    }
    upd[(size_t)i2 * 128 + lane]      = 0.9f * u0 + 0.1f * anc0;
    upd[(size_t)i2 * 128 + lane + 64] = 0.9f * u1 + 0.1f * anc1;
  }
}

// ------------------------------------------------------------------
// dec1: D = relu(LN(UPD[N,128] @ W[128,512] + b))
// 256 thr, 8 rows/block, thread = cols (t, t+256); float4-k.
__global__ __launch_bounds__(256) void k_dec1(const float* __restrict__ X,
    const float* __restrict__ W, const float* __restrict__ b,
    const float* __restrict__ g, const float* __restrict__ be,
    float* __restrict__ out) {
  __shared__ float xs[8][128];
  __shared__ float hs[8][512];
  const int t = threadIdx.x;
  const int row0 = blockIdx.x * 8;
  {
    const float4* src = reinterpret_cast<const float4*>(X + row0 * 128);
    float4* dst = reinterpret_cast<float4*>(&xs[0][0]);
    dst[t] = src[t];
  }
  __syncthreads();
  float acc0[8], acc1[8];
#pragma unroll
  for (int r = 0; r < 8; ++r) { acc0[r] = 0.f; acc1[r] = 0.f; }
  for (int k4 = 0; k4 < 32; ++k4) {
    const int k = k4 * 4;
    const float w00 = W[(k + 0) * 512 + t];
    const float w01 = W[(k + 1) * 512 + t];
    const float w02 = W[(k + 2) * 512 + t];
    const float w03 = W[(k + 3) * 512 + t];
    const float w10 = W[(k + 0) * 512 + t + 256];
    const float w11 = W[(k + 1) * 512 + t + 256];
    const float w12 = W[(k + 2) * 512 + t + 256];
    const float w13 = W[(k + 3) * 512 + t + 256];
#pragma unroll
    for (int r = 0; r < 8; ++r) {
      const float4 xv = *reinterpret_cast<const float4*>(&xs[r][k]);
      acc0[r] = fmaf(xv.x, w00, fmaf(xv.y, w01, fmaf(xv.z, w02, fmaf(xv.w, w03, acc0[r]))));
      acc1[r] = fmaf(xv.x, w10, fmaf(xv.y, w11, fmaf(xv.z, w12, fmaf(xv.w, w13, acc1[r]))));
    }
  }
  const float b0 = b[t], b1 = b[t + 256];
#pragma unroll
  for (int r = 0; r < 8; ++r) { hs[r][t] = acc0[r] + b0; hs[r][t + 256] = acc1[r] + b1; }
  __syncthreads();
  const int wv = t >> 6, lane = t & 63;
  for (int rr = 0; rr < 2; ++rr) {
    const int row = wv * 2 + rr;
    float v0[8];
    float s1 = 0.f, s2 = 0.f;
#pragma unroll
    for (int kk = 0; kk < 8; ++kk) {
      float x = hs[row][lane + 64 * kk];
      v0[kk] = x; s1 += x; s2 += x * x;
    }
#pragma unroll
    for (int off = 1; off < 64; off <<= 1) { s1 += __shfl_xor(s1, off); s2 += __shfl_xor(s2, off); }
    const float mean = s1 * (1.f / 512.f);
    const float rstd = rsqrtf(s2 * (1.f / 512.f) - mean * mean + 1e-5f);
#pragma unroll
    for (int kk = 0; kk < 8; ++kk) {
      int c = lane + 64 * kk;
      float y = g[c] * (v0[kk] - mean) * rstd + be[c];
      out[(row0 + row) * 512 + c] = fmaxf(y, 0.f);
    }
  }
}

// dec2: out = D[N,512] @ W[512,256] + b; 256 thr, 8 rows, 1 col; float4-k.
__global__ __launch_bounds__(256) void k_dec2(const float* __restrict__ X,
    const float* __restrict__ W, const float* __restrict__ b, float* __restrict__ out) {
  __shared__ float xs[8][512];
  const int t = threadIdx.x;
  const int row0 = blockIdx.x * 8;
  {
    const float4* src = reinterpret_cast<const float4*>(X + row0 * 512);
    float4* dst = reinterpret_cast<float4*>(&xs[0][0]);
#pragma unroll
    for (int u = 0; u < 4; ++u) dst[t + 256 * u] = src[t + 256 * u];
  }
  __syncthreads();
  float acc[8];
#pragma unroll
  for (int r = 0; r < 8; ++r) acc[r] = 0.f;
  for (int k4 = 0; k4 < 128; ++k4) {
    const int k = k4 * 4;
    const float w0 = W[(k + 0) * 256 + t];
    const float w1 = W[(k + 1) * 256 + t];
    const float w2 = W[(k + 2) * 256 + t];
    const float w3 = W[(k + 3) * 256 + t];
#pragma unroll
    for (int r = 0; r < 8; ++r) {
      const float4 xv = *reinterpret_cast<const float4*>(&xs[r][k]);
      acc[r] = fmaf(xv.x, w0, fmaf(xv.y, w1, fmaf(xv.z, w2, fmaf(xv.w, w3, acc[r]))));
    }
  }
  const float bb = b[t];
#pragma unroll
  for (int r = 0; r < 8; ++r) out[(row0 + r) * 256 + t] = acc[r] + bb;
}

// ------------------------------------------------------------------
extern "C" void kernel_launch(void* const* d_in, const int* in_sizes, int n_in,
                              void* d_out, int out_size, void* d_ws, size_t ws_size,
                              hipStream_t stream) {
  const float* lora   = (const float*)d_in[0];
  const float* temps  = (const float*)d_in[1];
  const int*   adj    = (const int*)d_in[2];
  const float* mb     = (const float*)d_in[3];
  const float* enc_W1 = (const float*)d_in[4];
  const float* enc_b1 = (const float*)d_in[5];
  const float* enc_g1 = (const float*)d_in[6];
  const float* enc_be1= (const float*)d_in[7];
  const float* enc_W2 = (const float*)d_in[8];
  const float* enc_b2 = (const float*)d_in[9];
  const float* enc_g2 = (const float*)d_in[10];
  const float* enc_be2= (const float*)d_in[11];
  const float* temp_W = (const float*)d_in[12];
  const float* temp_b = (const float*)d_in[13];
  const float* Wq     = (const float*)d_in[14];
  const float* Wk     = (const float*)d_in[15];
  const float* Wv     = (const float*)d_in[16];
  const float* Wo     = (const float*)d_in[17];
  const float* g_wa   = (const float*)d_in[18];
  const float* g_wb   = (const float*)d_in[19];
  const float* g_b    = (const float*)d_in[20];
  const float* dec_W1 = (const float*)d_in[21];
  const float* dec_b1 = (const float*)d_in[22];
  const float* dec_g1 = (const float*)d_in[23];
  const float* dec_be1= (const float*)d_in[24];
  const float* dec_W2 = (const float*)d_in[25];
  const float* dec_b2 = (const float*)d_in[26];

  float* ws = (float*)d_ws;
  float* H1  = ws;                      // N*512 (reused as DEC later)
  float* EMB = H1 + (size_t)N * 512;
  float* Q   = EMB + (size_t)N * 128;
  float* K   = Q + (size_t)N * 128;
  float* V   = K + (size_t)N * 128;
  float* ATT = V + (size_t)N * 128;     // reused as UPD later
  float* CTX = ATT + (size_t)N * 128;
  float* TI  = CTX + (size_t)N * 128;
  float* CJ  = TI + N;
  float* PA  = CJ + N;                  // SPLIT_ATT*N*128 (reused as GA: 8*N*128)
  float* PML = PA + (size_t)SPLIT_ATT * N * 128;  // SPLIT_ATT*N*NHEAD*2 (reused as GC: 8*N)
  unsigned int* BMW = (unsigned int*)(PML + (size_t)SPLIT_ATT * N * NHEAD * 2);
  float* UPD = ATT;
  float* GA  = PA;
  float* GC  = PML;
  float* DEC = H1;

  k_bm<<<512, 256, 0, stream>>>(adj, BMW);
  k_enc1<<<N / 8, 256, 0, stream>>>(lora, enc_W1, enc_b1, enc_g1, enc_be1, H1);
  k_enc2<<<N / 8, 256, 0, stream>>>(H1, enc_W2, enc_b2, enc_g2, enc_be2, EMB);
  k_ti<<<N / 64, 256, 0, stream>>>(temps, temp_W, temp_b, g_wa, TI);
  k_qkv<<<N / 16, 512, 0, stream>>>(EMB, Wq, Wk, Wv, Q, K, V);
  k_attn<<<(N / 64) * SPLIT_ATT, 256, 0, stream>>>(Q, K, V, BMW, PA, PML);
  k_attn_comb<<<(N * 128) / 256, 256, 0, stream>>>(PA, PML, ATT);
  k_ctx<<<N / 16, 512, 0, stream>>>(ATT, Wo, g_wb, CTX, CJ);
  k_gate<<<(N / 64) * SPLIT_G, 256, 0, stream>>>(CTX, CJ, TI, BMW, g_b, GA, GC);
  k_gcomb<<<N / 2, 256, 0, stream>>>(GA, GC, EMB, mb, UPD);
  k_dec1<<<N / 8, 256, 0, stream>>>(UPD, dec_W1, dec_b1, dec_g1, dec_be1, DEC);
  k_dec2<<<N / 8, 256, 0, stream>>>(DEC, dec_W2, dec_b2, (float*)d_out);
}